// Round 3
// baseline (691.670 us; speedup 1.0000x reference)
//
#include <hip/hip_runtime.h>
#include <cmath>

typedef __bf16  v8bf  __attribute__((ext_vector_type(8)));
typedef float   v4f   __attribute__((ext_vector_type(4)));

#define HH 56
#define WW2 56
#define SS 3
#define HEADS 6
#define DIM 192
#define HID 768
#define NTOK 49
#define NWIN 2048            // BATCH * 64
#define MTOT (NWIN * NTOK)   // 100352
#define SCALE 0.17677669529663687f

// region id in shifted-image coords: [0,49)=0, [49,53)=1, [53,56)=2
__device__ __forceinline__ int regid(int i) { return (i < 49) ? 0 : ((i < 53) ? 1 : 2); }

// async global->LDS, 16B per lane. LDS dest must be wave-uniform base + lane*16.
__device__ __forceinline__ void async_cp16(const __bf16* g, __bf16* l) {
    __builtin_amdgcn_global_load_lds(
        (const __attribute__((address_space(1))) void*)g,
        (__attribute__((address_space(3))) void*)l,
        16, 0, 0);
}

// ---------------------------------------------------------------------------
// Weight transpose + f32->bf16 cast: out[n*K + k] = (bf16)in[k*N + n]
// ---------------------------------------------------------------------------
__global__ void k_transpose(const float* __restrict__ in, __bf16* __restrict__ out,
                            int K, int N) {
    int idx = blockIdx.x * 256 + threadIdx.x;
    if (idx >= K * N) return;
    int n = idx / K, k = idx - n * K;
    out[idx] = (__bf16)in[k * N + n];
}

// ---------------------------------------------------------------------------
// LN1 + cyclic shift(-3,-3) + window partition. x f32 -> xw bf16 [w*49+p][c].
// ---------------------------------------------------------------------------
__global__ __launch_bounds__(256) void k_ln1win(const float* __restrict__ x,
                                                const float* __restrict__ g,
                                                const float* __restrict__ bt,
                                                __bf16* __restrict__ xw) {
    int wv = threadIdx.x >> 6, lane = threadIdx.x & 63;
    int t = blockIdx.x * 4 + wv;
    int w = t / NTOK, p = t - w * NTOK;
    int b = w >> 6, wi = w & 63;
    int i = (wi >> 3) * 7 + p / 7;
    int j = (wi & 7) * 7 + p % 7;
    int io = i + SS; if (io >= HH) io -= HH;
    int jo = j + SS; if (jo >= WW2) jo -= WW2;
    const float* src = x + ((size_t)(b * 3136 + io * 56 + jo)) * DIM;
    float v0 = src[lane], v1 = src[lane + 64], v2 = src[lane + 128];
    float s = v0 + v1 + v2, s2 = v0 * v0 + v1 * v1 + v2 * v2;
    #pragma unroll
    for (int off = 1; off < 64; off <<= 1) {
        s  += __shfl_xor(s, off);
        s2 += __shfl_xor(s2, off);
    }
    float mu = s * (1.f / 192.f);
    float rstd = rsqrtf(s2 * (1.f / 192.f) - mu * mu + 1e-5f);
    __bf16* dst = xw + (size_t)t * DIM;
    dst[lane]       = (__bf16)((v0 - mu) * rstd * g[lane]       + bt[lane]);
    dst[lane + 64]  = (__bf16)((v1 - mu) * rstd * g[lane + 64]  + bt[lane + 64]);
    dst[lane + 128] = (__bf16)((v2 - mu) * rstd * g[lane + 128] + bt[lane + 128]);
}

// ---------------------------------------------------------------------------
// LN2: x1 f32 [t][192] -> a2 bf16 [t][192]. One wave per row.
// ---------------------------------------------------------------------------
__global__ __launch_bounds__(256) void k_ln2(const float* __restrict__ x1,
                                             const float* __restrict__ g,
                                             const float* __restrict__ bt,
                                             __bf16* __restrict__ a2) {
    int wv = threadIdx.x >> 6, lane = threadIdx.x & 63;
    int t = blockIdx.x * 4 + wv;
    const float* src = x1 + (size_t)t * DIM;
    float v0 = src[lane], v1 = src[lane + 64], v2 = src[lane + 128];
    float s = v0 + v1 + v2, s2 = v0 * v0 + v1 * v1 + v2 * v2;
    #pragma unroll
    for (int off = 1; off < 64; off <<= 1) {
        s  += __shfl_xor(s, off);
        s2 += __shfl_xor(s2, off);
    }
    float mu = s * (1.f / 192.f);
    float rstd = rsqrtf(s2 * (1.f / 192.f) - mu * mu + 1e-5f);
    __bf16* dst = a2 + (size_t)t * DIM;
    dst[lane]       = (__bf16)((v0 - mu) * rstd * g[lane]       + bt[lane]);
    dst[lane + 64]  = (__bf16)((v1 - mu) * rstd * g[lane + 64]  + bt[lane + 64]);
    dst[lane + 128] = (__bf16)((v2 - mu) * rstd * g[lane + 128] + bt[lane + 128]);
}

// ---------------------------------------------------------------------------
// 128x128-tile MFMA GEMM (m97 structure): C = A[MxK] * Wt[NxK]^T + bias.
// 4 waves, each 64x64 (4x4 of 16x16x32). global_load_lds width-16 staging.
// MODE 0: qkv  -> outb [M][576] bf16, q cols (<192) scaled
// MODE 1: proj -> outf = x1 (window-reverse scatter) + xres, f32
// MODE 2: fc1  -> outb [M][768] bf16 with exact-erf GELU
// MODE 3: fc2  -> outf [M][192] f32 = v + bias + x1in (row-major residual)
// ---------------------------------------------------------------------------
template<int KDIM, int NDIM, int MODE>
__global__ __launch_bounds__(256) void k_gemm128(const __bf16* __restrict__ A,
                                                 const __bf16* __restrict__ Wt,
                                                 const float* __restrict__ bias,
                                                 __bf16* __restrict__ outb,
                                                 const float* __restrict__ x1in,
                                                 float* __restrict__ outf,
                                                 const float* __restrict__ xres) {
    __shared__ __bf16 lA[128 * 32];
    __shared__ __bf16 lB[128 * 32];
    const int tid = threadIdx.x;
    const int m0 = blockIdx.x * 128, n0 = blockIdx.y * 128;
    const int wv = tid >> 6, lane = tid & 63;
    const int wm = (wv >> 1) * 64, wn = (wv & 1) * 64;
    const int lrow = lane & 15, lq = lane >> 4;
    const int grow = tid >> 2, gkc = (tid & 3) * 8;
    v4f acc[4][4] = {};
    for (int kk = 0; kk < KDIM; kk += 32) {
        #pragma unroll
        for (int c = 0; c < 2; c++) {
            int r = grow + c * 64;
            async_cp16(A + (size_t)(m0 + r) * KDIM + kk + gkc, lA + tid * 8 + c * 2048);
            int rb = n0 + r;
            if (NDIM % 128) rb = (rb < NDIM) ? rb : (NDIM - 1);
            async_cp16(Wt + (size_t)rb * KDIM + kk + gkc, lB + tid * 8 + c * 2048);
        }
        __syncthreads();
        v8bf af[4], bf[4];
        #pragma unroll
        for (int i = 0; i < 4; i++) {
            af[i] = *(const v8bf*)(lA + (wm + i * 16 + lrow) * 32 + lq * 8);
            bf[i] = *(const v8bf*)(lB + (wn + i * 16 + lrow) * 32 + lq * 8);
        }
        #pragma unroll
        for (int i = 0; i < 4; i++)
        #pragma unroll
        for (int j = 0; j < 4; j++)
            acc[i][j] = __builtin_amdgcn_mfma_f32_16x16x32_bf16(af[i], bf[j], acc[i][j], 0, 0, 0);
        __syncthreads();
    }
    #pragma unroll
    for (int i = 0; i < 4; i++)
    #pragma unroll
    for (int j = 0; j < 4; j++) {
        int col = n0 + wn + j * 16 + lrow;
        if (NDIM % 128 && col >= NDIM) continue;
        float bv = bias[col];
        #pragma unroll
        for (int r = 0; r < 4; r++) {
            int row = m0 + wm + i * 16 + lq * 4 + r;
            float v = acc[i][j][r] + bv;
            if (MODE == 0) {
                if (col < DIM) v *= SCALE;
                outb[(size_t)row * 576 + col] = (__bf16)v;
            } else if (MODE == 2) {
                float ge = 0.5f * v * (1.f + erff(v * 0.70710678118654752f));
                outb[(size_t)row * HID + col] = (__bf16)ge;
            } else if (MODE == 3) {
                size_t o = (size_t)row * DIM + col;
                outf[o] = v + x1in[o];
            } else {  // proj: window-reverse + unshift + residual
                int w = row / NTOK, p = row - w * NTOK;
                int bimg = w >> 6, wi = w & 63;
                int ii = (wi >> 3) * 7 + p / 7;
                int jj = (wi & 7) * 7 + p % 7;
                int io = ii + SS; if (io >= HH) io -= HH;
                int jo = jj + SS; if (jo >= WW2) jo -= WW2;
                size_t o = ((size_t)(bimg * 3136 + io * 56 + jo)) * DIM + col;
                outf[o] = v + xres[o];
            }
        }
    }
}

// ---------------------------------------------------------------------------
// Windowed attention: one wave per (window, head). qkv interleaved [t][576].
// ---------------------------------------------------------------------------
#define KVS 36   // padded LDS row stride (floats) for K/V
__global__ __launch_bounds__(64) void k_attn(const __bf16* __restrict__ qkvb,
                                             const float* __restrict__ rpb,
                                             __bf16* __restrict__ ao) {
    __shared__ float Kf[NTOK * KVS];
    __shared__ float Vf[NTOK * KVS];
    __shared__ float Sm[NTOK * NTOK];
    __shared__ float rl[169];
    int w = blockIdx.x, h = blockIdx.y;
    int tid = threadIdx.x;
    const __bf16* base = qkvb + (size_t)(w * NTOK) * 576 + h * 32;
    for (int idx = tid; idx < NTOK * 4; idx += 64) {
        int t = idx >> 2, c = (idx & 3) * 8;
        v8bf kv = *(const v8bf*)(base + (size_t)t * 576 + 192 + c);
        v8bf vv = *(const v8bf*)(base + (size_t)t * 576 + 384 + c);
        #pragma unroll
        for (int jj = 0; jj < 8; jj++) {
            Kf[t * KVS + c + jj] = (float)kv[jj];
            Vf[t * KVS + c + jj] = (float)vv[jj];
        }
    }
    for (int idx = tid; idx < 169; idx += 64) rl[idx] = rpb[idx * 6 + h];
    __syncthreads();
    if (tid < NTOK) {
        int wi = w & 63;
        int i0 = (wi >> 3) * 7, j0 = (wi & 7) * 7;
        int ni = tid / 7, nj = tid - ni * 7;
        int cn = regid(i0 + ni) * 3 + regid(j0 + nj);
        float4 qr4[8];
        float* Qf = (float*)qr4;
        const __bf16* qp = base + (size_t)tid * 576;
        #pragma unroll
        for (int g = 0; g < 4; g++) {
            v8bf qv = *(const v8bf*)(qp + g * 8);
            #pragma unroll
            for (int jj = 0; jj < 8; jj++) Qf[g * 8 + jj] = (float)qv[jj];
        }
        float* Srow = Sm + tid * NTOK;
        float mx = -1e30f;
        for (int mi = 0; mi < 7; mi++) {
            int crm = regid(i0 + mi) * 3;
            for (int mj = 0; mj < 7; mj++) {
                int m = mi * 7 + mj;
                const float4* kp = (const float4*)(Kf + m * KVS);
                float accv = 0.f;
                #pragma unroll
                for (int c = 0; c < 8; c++) {
                    float4 kv = kp[c];
                    float4 qv = qr4[c];
                    accv += qv.x * kv.x + qv.y * kv.y + qv.z * kv.z + qv.w * kv.w;
                }
                accv += rl[(ni - mi + 6) * 13 + (nj - mj + 6)];
                int cm = crm + regid(j0 + mj);
                accv += (cm == cn) ? 0.f : -100.f;
                mx = fmaxf(mx, accv);
                Srow[m] = accv;
            }
        }
        float den = 0.f;
        for (int m = 0; m < NTOK; m++) {
            float pp = __expf(Srow[m] - mx);
            den += pp;
            Srow[m] = pp;
        }
        float4 O4[8] = {};
        float* Of = (float*)O4;
        for (int m = 0; m < NTOK; m++) {
            float pp = Srow[m];
            const float4* vp = (const float4*)(Vf + m * KVS);
            #pragma unroll
            for (int c = 0; c < 8; c++) {
                float4 vvv = vp[c];
                O4[c].x += pp * vvv.x; O4[c].y += pp * vvv.y;
                O4[c].z += pp * vvv.z; O4[c].w += pp * vvv.w;
            }
        }
        float inv = 1.f / den;
        __bf16* aop = ao + ((size_t)(w * NTOK + tid)) * DIM + h * 32;
        #pragma unroll
        for (int g = 0; g < 4; g++) {
            v8bf o8;
            #pragma unroll
            for (int jj = 0; jj < 8; jj++) o8[jj] = (__bf16)(Of[g * 8 + jj] * inv);
            *(v8bf*)(aop + g * 8) = o8;
        }
    }
}

// ---------------------------------------------------------------------------
// Fallback fused MLP (used only if ws_size is too small for the hidden buf).
// ---------------------------------------------------------------------------
__global__ __launch_bounds__(256) void k_mlp(const float* __restrict__ x1,
                                             const float* __restrict__ n2g,
                                             const float* __restrict__ n2b,
                                             const __bf16* __restrict__ fc1T,
                                             const float* __restrict__ fc1b,
                                             const __bf16* __restrict__ fc2T,
                                             const float* __restrict__ fc2b,
                                             float* __restrict__ out) {
    __shared__ __align__(16) char sm[75776];
    __bf16* aT  = (__bf16*)sm;
    float*  lnf = (float*)(sm + 25600);
    __bf16* lB  = (__bf16*)(sm + 25600);
    __bf16* lH  = (__bf16*)(sm + 40960);
    int tid = threadIdx.x;
    int m0 = blockIdx.x * 64;
    int wv = tid >> 6, lane = tid & 63;
    int lrow = lane & 15, lq = lane >> 4;
    int wm = (wv >> 1) * 32, wnb = wv & 1;
    #pragma unroll
    for (int c = 0; c < 12; c++) {
        int idx = tid + c * 256;
        int row = idx / 48, c4 = (idx - row * 48) * 4;
        *(float4*)(lnf + row * 196 + c4) = *(const float4*)(x1 + (size_t)(m0 + row) * DIM + c4);
    }
    __syncthreads();
    {
        int row = tid >> 2, part = tid & 3;
        const float* rp = lnf + row * 196;
        float s = 0.f, s2 = 0.f;
        for (int i = part * 48; i < part * 48 + 48; i++) { float vv = rp[i]; s += vv; s2 += vv * vv; }
        s += __shfl_xor(s, 1); s2 += __shfl_xor(s2, 1);
        s += __shfl_xor(s, 2); s2 += __shfl_xor(s2, 2);
        float mu = s * (1.f / 192.f);
        float rstd = rsqrtf(s2 * (1.f / 192.f) - mu * mu + 1e-5f);
        __bf16* ap = aT + row * 200;
        for (int i = part * 48; i < part * 48 + 48; i++)
            ap[i] = (__bf16)((rp[i] - mu) * rstd * n2g[i] + n2b[i]);
    }
    __syncthreads();
    v4f yacc[2][6] = {};
    for (int hc = 0; hc < 6; hc++) {
        v4f hacc[2][4] = {};
        for (int ks = 0; ks < 6; ks++) {
            #pragma unroll
            for (int c = 0; c < 2; c++) {
                int nrow = (tid >> 2) + c * 64;
                int kc = (tid & 3) * 8;
                *(v8bf*)(lB + nrow * 40 + kc) =
                    *(const v8bf*)(fc1T + (size_t)(hc * 128 + nrow) * DIM + ks * 32 + kc);
            }
            __syncthreads();
            #pragma unroll
            for (int a = 0; a < 2; a++) {
                v8bf af = *(const v8bf*)(aT + (wm + a * 16 + lrow) * 200 + ks * 32 + lq * 8);
                #pragma unroll
                for (int b = 0; b < 4; b++) {
                    v8bf bf = *(const v8bf*)(lB + (wnb * 64 + b * 16 + lrow) * 40 + lq * 8);
                    hacc[a][b] = __builtin_amdgcn_mfma_f32_16x16x32_bf16(af, bf, hacc[a][b], 0, 0, 0);
                }
            }
            __syncthreads();
        }
        #pragma unroll
        for (int a = 0; a < 2; a++)
        #pragma unroll
        for (int b = 0; b < 4; b++)
        #pragma unroll
        for (int r = 0; r < 4; r++) {
            int row = wm + a * 16 + lq * 4 + r;
            int col = wnb * 64 + b * 16 + lrow;
            float hv = hacc[a][b][r] + fc1b[hc * 128 + col];
            float ge = 0.5f * hv * (1.f + erff(hv * 0.70710678118654752f));
            lH[row * 136 + col] = (__bf16)ge;
        }
        __syncthreads();
        for (int k2 = 0; k2 < 4; k2++) {
            #pragma unroll
            for (int c = 0; c < 3; c++) {
                int nrow = (tid >> 2) + c * 64;
                int kc = (tid & 3) * 8;
                *(v8bf*)(lB + nrow * 40 + kc) =
                    *(const v8bf*)(fc2T + (size_t)nrow * HID + hc * 128 + k2 * 32 + kc);
            }
            __syncthreads();
            #pragma unroll
            for (int a = 0; a < 2; a++) {
                v8bf af = *(const v8bf*)(lH + (wm + a * 16 + lrow) * 136 + k2 * 32 + lq * 8);
                #pragma unroll
                for (int b = 0; b < 6; b++) {
                    v8bf bf = *(const v8bf*)(lB + (wnb * 96 + b * 16 + lrow) * 40 + lq * 8);
                    yacc[a][b] = __builtin_amdgcn_mfma_f32_16x16x32_bf16(af, bf, yacc[a][b], 0, 0, 0);
                }
            }
            __syncthreads();
        }
    }
    #pragma unroll
    for (int a = 0; a < 2; a++)
    #pragma unroll
    for (int b = 0; b < 6; b++)
    #pragma unroll
    for (int r = 0; r < 4; r++) {
        int grow = m0 + wm + a * 16 + lq * 4 + r;
        int col = wnb * 96 + b * 16 + lrow;
        float vv = yacc[a][b][r] + fc2b[col] + x1[(size_t)grow * DIM + col];
        out[(size_t)grow * DIM + col] = vv;
    }
}

// ---------------------------------------------------------------------------
extern "C" void kernel_launch(void* const* d_in, const int* in_sizes, int n_in,
                              void* d_out, int out_size, void* d_ws, size_t ws_size,
                              hipStream_t stream) {
    const float* x      = (const float*)d_in[0];
    const float* n1g    = (const float*)d_in[1];
    const float* n1b    = (const float*)d_in[2];
    const float* qkv_w  = (const float*)d_in[3];
    const float* qkv_b  = (const float*)d_in[4];
    const float* rpb    = (const float*)d_in[5];
    const float* proj_w = (const float*)d_in[6];
    const float* proj_b = (const float*)d_in[7];
    const float* n2g    = (const float*)d_in[8];
    const float* n2b    = (const float*)d_in[9];
    const float* fc1_w  = (const float*)d_in[10];
    const float* fc1_b  = (const float*)d_in[11];
    const float* fc2_w  = (const float*)d_in[12];
    const float* fc2_b  = (const float*)d_in[13];
    float* outp = (float*)d_out;

    char* ws = (char*)d_ws;
    const size_t SZA   = (size_t)MTOT * DIM * 2;    //  38,535,168
    const size_t SZQKV = (size_t)MTOT * 576 * 2;    // 115,605,504
    const size_t SZHID = (size_t)MTOT * HID * 2;    // 154,140,672
    const size_t SZX1  = (size_t)MTOT * DIM * 4;    //  77,070,336
    const size_t WSZ   = 884736;                    // transposed weights

    const size_t need_big = SZA + SZHID + SZX1 + WSZ;   // ~270.6 MB
    bool big = (ws_size >= need_big);

    __bf16* xw;  __bf16* qkvb; float* x1; __bf16* a2; __bf16* hid; char* wbase;
    if (big) {
        xw    = (__bf16*)(ws);                    // ln1 out; then attn out; a2 overlays
        qkvb  = (__bf16*)(ws + SZA);              // qkv out; hid overlays (same region)
        hid   = (__bf16*)(ws + SZA);
        x1    = (float*)(ws + SZA + SZHID);
        a2    = (__bf16*)(ws);                    // after proj, xw region is free
        wbase = ws + SZA + SZHID + SZX1;
    } else {
        xw    = (__bf16*)(ws);
        qkvb  = (__bf16*)(ws + SZA);
        x1    = (float*)(ws + SZA);               // overlays qkvb after attn
        a2    = nullptr; hid = nullptr;
        wbase = ws + SZA + SZQKV;
    }
    __bf16* qkvT = (__bf16*)wbase;
    __bf16* projT = qkvT + 576 * 192;
    __bf16* fc1T  = projT + 192 * 192;
    __bf16* fc2T  = fc1T + 768 * 192;

    k_transpose<<<(192 * 576 + 255) / 256, 256, 0, stream>>>(qkv_w, qkvT, 192, 576);
    k_transpose<<<(192 * 192 + 255) / 256, 256, 0, stream>>>(proj_w, projT, 192, 192);
    k_transpose<<<(192 * 768 + 255) / 256, 256, 0, stream>>>(fc1_w, fc1T, 192, 768);
    k_transpose<<<(768 * 192 + 255) / 256, 256, 0, stream>>>(fc2_w, fc2T, 768, 192);

    k_ln1win<<<MTOT / 4, 256, 0, stream>>>(x, n1g, n1b, xw);

    // qkv: [M x 192] x [576 x 192]^T -> qkvb [M][576]
    k_gemm128<192, 576, 0><<<dim3(MTOT / 128, 5), 256, 0, stream>>>(
        xw, qkvT, qkv_b, qkvb, nullptr, nullptr, nullptr);

    k_attn<<<dim3(NWIN, HEADS), 64, 0, stream>>>(qkvb, rpb, xw);

    // proj: [M x 192] x [192 x 192]^T -> x1 f32 (image order, +residual)
    k_gemm128<192, 192, 1><<<dim3(MTOT / 128, 2), 256, 0, stream>>>(
        xw, projT, proj_b, nullptr, nullptr, x1, x);

    if (big) {
        k_ln2<<<MTOT / 4, 256, 0, stream>>>(x1, n2g, n2b, a2);
        // fc1: [M x 192] x [768 x 192]^T -> hid bf16 (GELU)
        k_gemm128<192, 768, 2><<<dim3(MTOT / 128, 6), 256, 0, stream>>>(
            a2, fc1T, fc1_b, hid, nullptr, nullptr, nullptr);
        // fc2: [M x 768] x [192 x 768]^T -> out f32 (+bias +x1)
        k_gemm128<768, 192, 3><<<dim3(MTOT / 128, 2), 256, 0, stream>>>(
            hid, fc2T, fc2_b, nullptr, x1, outp, nullptr);
    } else {
        k_mlp<<<MTOT / 64, 256, 0, stream>>>(x1, n2g, n2b, fc1T, fc1_b, fc2T, fc2_b, outp);
    }
}

// Round 4
// 585.301 us; speedup vs baseline: 1.1817x; 1.1817x over previous
//
#include <hip/hip_runtime.h>
#include <cmath>

typedef __bf16  v8bf  __attribute__((ext_vector_type(8)));
typedef float   v4f   __attribute__((ext_vector_type(4)));

#define HH 56
#define WW2 56
#define SS 3
#define HEADS 6
#define DIM 192
#define HID 768
#define NTOK 49
#define NWIN 2048            // BATCH * 64
#define MTOT (NWIN * NTOK)   // 100352
#define SCALE 0.17677669529663687f

// async global->LDS, 16B per lane. LDS dest must be wave-uniform base + lane*16.
__device__ __forceinline__ void async_cp16(const __bf16* g, __bf16* l) {
    __builtin_amdgcn_global_load_lds(
        (const __attribute__((address_space(1))) void*)g,
        (__attribute__((address_space(3))) void*)l,
        16, 0, 0);
}

// ---------------------------------------------------------------------------
// Weight transpose + f32->bf16 cast: out[n*K + k] = (bf16)in[k*N + n]
// ---------------------------------------------------------------------------
__global__ void k_transpose(const float* __restrict__ in, __bf16* __restrict__ out,
                            int K, int N) {
    int idx = blockIdx.x * 256 + threadIdx.x;
    if (idx >= K * N) return;
    int n = idx / K, k = idx - n * K;
    out[idx] = (__bf16)in[k * N + n];
}

// ---------------------------------------------------------------------------
// Precompute bias tables: bias_tab[type][h][m][n], type in {0=interior,
// 1=right-edge, 2=bottom-edge, 3=corner}. Includes rel-pos bias, shift mask,
// and -1e9 padding for cols m>=49.  n-contiguous so attention loads float4.
// ---------------------------------------------------------------------------
__global__ void k_bias(const float* __restrict__ rpb, float* __restrict__ bt) {
    int type = blockIdx.x, h = blockIdx.y;
    for (int idx = threadIdx.x; idx < 4096; idx += 256) {
        int m = idx >> 6, n = idx & 63;
        float v;
        if (m >= 49) v = -1e9f;
        else if (n >= 49) v = 0.f;
        else {
            int ni = n / 7, nj = n % 7, mi = m / 7, mj = m % 7;
            v = rpb[((ni - mi + 6) * 13 + (nj - mj + 6)) * 6 + h];
            int rin = (type & 2) ? ((ni < 4) ? 1 : 2) : 0;
            int rjn = (type & 1) ? ((nj < 4) ? 1 : 2) : 0;
            int rim = (type & 2) ? ((mi < 4) ? 1 : 2) : 0;
            int rjm = (type & 1) ? ((mj < 4) ? 1 : 2) : 0;
            if (rin * 3 + rjn != rim * 3 + rjm) v -= 100.f;
        }
        bt[((size_t)(type * HEADS + h) * 64 + m) * 64 + n] = v;
    }
}

// ---------------------------------------------------------------------------
// LN1 + cyclic shift(-3,-3) + window partition. x f32 -> xw bf16 [w*49+p][c].
// ---------------------------------------------------------------------------
__global__ __launch_bounds__(256) void k_ln1win(const float* __restrict__ x,
                                                const float* __restrict__ g,
                                                const float* __restrict__ bt,
                                                __bf16* __restrict__ xw) {
    int wv = threadIdx.x >> 6, lane = threadIdx.x & 63;
    int t = blockIdx.x * 4 + wv;
    int w = t / NTOK, p = t - w * NTOK;
    int b = w >> 6, wi = w & 63;
    int i = (wi >> 3) * 7 + p / 7;
    int j = (wi & 7) * 7 + p % 7;
    int io = i + SS; if (io >= HH) io -= HH;
    int jo = j + SS; if (jo >= WW2) jo -= WW2;
    const float* src = x + ((size_t)(b * 3136 + io * 56 + jo)) * DIM;
    float v0 = src[lane], v1 = src[lane + 64], v2 = src[lane + 128];
    float s = v0 + v1 + v2, s2 = v0 * v0 + v1 * v1 + v2 * v2;
    #pragma unroll
    for (int off = 1; off < 64; off <<= 1) {
        s  += __shfl_xor(s, off);
        s2 += __shfl_xor(s2, off);
    }
    float mu = s * (1.f / 192.f);
    float rstd = rsqrtf(s2 * (1.f / 192.f) - mu * mu + 1e-5f);
    __bf16* dst = xw + (size_t)t * DIM;
    dst[lane]       = (__bf16)((v0 - mu) * rstd * g[lane]       + bt[lane]);
    dst[lane + 64]  = (__bf16)((v1 - mu) * rstd * g[lane + 64]  + bt[lane + 64]);
    dst[lane + 128] = (__bf16)((v2 - mu) * rstd * g[lane + 128] + bt[lane + 128]);
}

// ---------------------------------------------------------------------------
// LN2: x1 f32 [t][192] -> a2 bf16 [t][192]. One wave per row.
// ---------------------------------------------------------------------------
__global__ __launch_bounds__(256) void k_ln2(const float* __restrict__ x1,
                                             const float* __restrict__ g,
                                             const float* __restrict__ bt,
                                             __bf16* __restrict__ a2) {
    int wv = threadIdx.x >> 6, lane = threadIdx.x & 63;
    int t = blockIdx.x * 4 + wv;
    const float* src = x1 + (size_t)t * DIM;
    float v0 = src[lane], v1 = src[lane + 64], v2 = src[lane + 128];
    float s = v0 + v1 + v2, s2 = v0 * v0 + v1 * v1 + v2 * v2;
    #pragma unroll
    for (int off = 1; off < 64; off <<= 1) {
        s  += __shfl_xor(s, off);
        s2 += __shfl_xor(s2, off);
    }
    float mu = s * (1.f / 192.f);
    float rstd = rsqrtf(s2 * (1.f / 192.f) - mu * mu + 1e-5f);
    __bf16* dst = a2 + (size_t)t * DIM;
    dst[lane]       = (__bf16)((v0 - mu) * rstd * g[lane]       + bt[lane]);
    dst[lane + 64]  = (__bf16)((v1 - mu) * rstd * g[lane + 64]  + bt[lane + 64]);
    dst[lane + 128] = (__bf16)((v2 - mu) * rstd * g[lane + 128] + bt[lane + 128]);
}

// ---------------------------------------------------------------------------
// 128x128-tile MFMA GEMM: C = A[MxK] * Wt[NxK]^T + bias.
// MODE 0: qkv scatter -> qb/kb/vb [w,h,t,32] bf16 (q scaled); kb/vb derived.
// MODE 1: proj -> outf = x1 (window-reverse scatter) + xres, f32
// MODE 2: fc1  -> outb [M][768] bf16 with exact-erf GELU
// MODE 3: fc2  -> outf [M][192] f32 = v + bias + x1in
// ---------------------------------------------------------------------------
template<int KDIM, int NDIM, int MODE>
__global__ __launch_bounds__(256) void k_gemm128(const __bf16* __restrict__ A,
                                                 const __bf16* __restrict__ Wt,
                                                 const float* __restrict__ bias,
                                                 __bf16* __restrict__ outb,
                                                 const float* __restrict__ x1in,
                                                 float* __restrict__ outf,
                                                 const float* __restrict__ xres) {
    __shared__ __bf16 lA[128 * 32];
    __shared__ __bf16 lB[128 * 32];
    const int tid = threadIdx.x;
    const int m0 = blockIdx.x * 128, n0 = blockIdx.y * 128;
    const int wv = tid >> 6, lane = tid & 63;
    const int wm = (wv >> 1) * 64, wn = (wv & 1) * 64;
    const int lrow = lane & 15, lq = lane >> 4;
    const int grow = tid >> 2, gkc = (tid & 3) * 8;
    v4f acc[4][4] = {};
    for (int kk = 0; kk < KDIM; kk += 32) {
        #pragma unroll
        for (int c = 0; c < 2; c++) {
            int r = grow + c * 64;
            async_cp16(A + (size_t)(m0 + r) * KDIM + kk + gkc, lA + tid * 8 + c * 2048);
            int rb = n0 + r;
            if (NDIM % 128) rb = (rb < NDIM) ? rb : (NDIM - 1);
            async_cp16(Wt + (size_t)rb * KDIM + kk + gkc, lB + tid * 8 + c * 2048);
        }
        __syncthreads();
        v8bf af[4], bf[4];
        #pragma unroll
        for (int i = 0; i < 4; i++) {
            af[i] = *(const v8bf*)(lA + (wm + i * 16 + lrow) * 32 + lq * 8);
            bf[i] = *(const v8bf*)(lB + (wn + i * 16 + lrow) * 32 + lq * 8);
        }
        #pragma unroll
        for (int i = 0; i < 4; i++)
        #pragma unroll
        for (int j = 0; j < 4; j++)
            acc[i][j] = __builtin_amdgcn_mfma_f32_16x16x32_bf16(af[i], bf[j], acc[i][j], 0, 0, 0);
        __syncthreads();
    }
    #pragma unroll
    for (int i = 0; i < 4; i++)
    #pragma unroll
    for (int j = 0; j < 4; j++) {
        int col = n0 + wn + j * 16 + lrow;
        if (NDIM % 128 && col >= NDIM) continue;
        float bv = bias[col];
        #pragma unroll
        for (int r = 0; r < 4; r++) {
            int row = m0 + wm + i * 16 + lq * 4 + r;
            float v = acc[i][j][r] + bv;
            if (MODE == 0) {
                __bf16* kbp = outb + (size_t)MTOT * DIM;
                __bf16* vbp = kbp + (size_t)MTOT * DIM;
                int which = col / DIM, rem = col - which * DIM;
                int hh = rem >> 5, d = rem & 31;
                int w = row / NTOK, p = row - w * NTOK;
                size_t off = ((size_t)(w * HEADS + hh) * NTOK + p) * 32 + d;
                if (which == 0)      outb[off] = (__bf16)(v * SCALE);
                else if (which == 1) kbp[off] = (__bf16)v;
                else                 vbp[off] = (__bf16)v;
            } else if (MODE == 2) {
                float ge = 0.5f * v * (1.f + erff(v * 0.70710678118654752f));
                outb[(size_t)row * HID + col] = (__bf16)ge;
            } else if (MODE == 3) {
                size_t o = (size_t)row * DIM + col;
                outf[o] = v + x1in[o];
            } else {  // proj: window-reverse + unshift + residual
                int w = row / NTOK, p = row - w * NTOK;
                int bimg = w >> 6, wi = w & 63;
                int ii = (wi >> 3) * 7 + p / 7;
                int jj = (wi & 7) * 7 + p % 7;
                int io = ii + SS; if (io >= HH) io -= HH;
                int jo = jj + SS; if (jo >= WW2) jo -= WW2;
                size_t o = ((size_t)(bimg * 3136 + io * 56 + jo)) * DIM + col;
                outf[o] = v + xres[o];
            }
        }
    }
}

// ---------------------------------------------------------------------------
// MFMA windowed attention: one wave per (window, head), 64-thread blocks.
// S = Q·K^T via 16 mfma_16x16x32_bf16; softmax in C-layout (shfl over the
// 16-lane col groups); P -> LDS (bf16, stride 72) -> A-frags; V transposed
// into LDS VT[32][72]; PV via 16 more MFMAs; divide by denom in epilogue.
// bias_tab folds rel-pos bias + shift mask + col-pad(-1e9).
// ---------------------------------------------------------------------------
__global__ __launch_bounds__(64) void k_attn_mfma(const __bf16* __restrict__ qb,
                                                  const float* __restrict__ bias_tab,
                                                  __bf16* __restrict__ ao) {
    __shared__ __bf16 Pl[64 * 72];
    __shared__ __bf16 VTl[32 * 72];
    const __bf16* kb = qb + (size_t)MTOT * DIM;
    const __bf16* vb = kb + (size_t)MTOT * DIM;
    int wh = blockIdx.x;
    int w = wh / HEADS, h = wh - w * HEADS;
    int lane = threadIdx.x & 63;
    int c = lane & 15, q = lane >> 4;
    const size_t base = (size_t)wh * (NTOK * 32);

    // zero VT pad cols 48..63 (pad cols multiply P=0; must be finite)
    for (int idx = lane; idx < 32 * 16; idx += 64)
        VTl[(idx >> 4) * 72 + 48 + (idx & 15)] = (__bf16)0.f;
    // build VT[d][t] = V[t][d]
    #pragma unroll
    for (int it = 0; it < 4; it++) {
        int idx = it * 64 + lane;
        if (idx < NTOK * 4) {
            int t = idx >> 2, d0 = (idx & 3) * 8;
            v8bf vv = *(const v8bf*)(vb + base + t * 32 + d0);
            #pragma unroll
            for (int ii = 0; ii < 8; ii++) VTl[(d0 + ii) * 72 + t] = vv[ii];
        }
    }
    // Q (A-frag) and K (B-frag) direct from global, rows clamped to 48
    v8bf af[4], bf[4];
    #pragma unroll
    for (int rt = 0; rt < 4; rt++) {
        int t = rt * 16 + c; t = (t > 48) ? 48 : t;
        af[rt] = *(const v8bf*)(qb + base + t * 32 + q * 8);
        bf[rt] = *(const v8bf*)(kb + base + t * 32 + q * 8);
    }
    v4f S[4][4] = {};
    #pragma unroll
    for (int rt = 0; rt < 4; rt++)
    #pragma unroll
    for (int ct = 0; ct < 4; ct++)
        S[rt][ct] = __builtin_amdgcn_mfma_f32_16x16x32_bf16(af[rt], bf[ct], S[rt][ct], 0, 0, 0);
    // bias + mask + pad from table (wave-uniform window type)
    int wi = w & 63;
    int type = (((wi >> 3) == 7) ? 2 : 0) + (((wi & 7) == 7) ? 1 : 0);
    const float* bt = bias_tab + (size_t)(type * HEADS + h) * 4096;
    #pragma unroll
    for (int rt = 0; rt < 4; rt++)
    #pragma unroll
    for (int ct = 0; ct < 4; ct++) {
        v4f bv = *(const v4f*)(bt + (ct * 16 + c) * 64 + rt * 16 + q * 4);
        S[rt][ct] += bv;
    }
    // softmax over cols (m): rows live in (q,reg), cols across 16 c-lanes x 4 ct
    v4f mx4[4], inv4[4];
    #pragma unroll
    for (int rt = 0; rt < 4; rt++) {
        v4f m;
        #pragma unroll
        for (int r = 0; r < 4; r++)
            m[r] = fmaxf(fmaxf(S[rt][0][r], S[rt][1][r]), fmaxf(S[rt][2][r], S[rt][3][r]));
        #pragma unroll
        for (int off = 1; off < 16; off <<= 1) {
            #pragma unroll
            for (int r = 0; r < 4; r++) m[r] = fmaxf(m[r], __shfl_xor(m[r], off));
        }
        mx4[rt] = m;
    }
    #pragma unroll
    for (int rt = 0; rt < 4; rt++) {
        v4f dsum = {};
        #pragma unroll
        for (int ct = 0; ct < 4; ct++) {
            #pragma unroll
            for (int r = 0; r < 4; r++) {
                float e = __expf(S[rt][ct][r] - mx4[rt][r]);
                dsum[r] += e;
                Pl[(rt * 16 + q * 4 + r) * 72 + ct * 16 + c] = (__bf16)e;
            }
        }
        #pragma unroll
        for (int off = 1; off < 16; off <<= 1) {
            #pragma unroll
            for (int r = 0; r < 4; r++) dsum[r] += __shfl_xor(dsum[r], off);
        }
        #pragma unroll
        for (int r = 0; r < 4; r++) inv4[rt][r] = 1.f / dsum[r];
    }
    __syncthreads();   // order P/VT writes before fragment reads (single wave)
    // O = P·V
    v4f O[4][2] = {};
    #pragma unroll
    for (int k2 = 0; k2 < 2; k2++) {
        v8bf pa[4], pb[2];
        #pragma unroll
        for (int rt = 0; rt < 4; rt++)
            pa[rt] = *(const v8bf*)(Pl + (rt * 16 + c) * 72 + k2 * 32 + q * 8);
        #pragma unroll
        for (int ct = 0; ct < 2; ct++)
            pb[ct] = *(const v8bf*)(VTl + (ct * 16 + c) * 72 + k2 * 32 + q * 8);
        #pragma unroll
        for (int rt = 0; rt < 4; rt++)
        #pragma unroll
        for (int ct = 0; ct < 2; ct++)
            O[rt][ct] = __builtin_amdgcn_mfma_f32_16x16x32_bf16(pa[rt], pb[ct], O[rt][ct], 0, 0, 0);
    }
    // store (normalize): ao[w*49+row][h*32 + d]
    __bf16* aop = ao + (size_t)(w * NTOK) * DIM + h * 32;
    #pragma unroll
    for (int rt = 0; rt < 4; rt++)
    #pragma unroll
    for (int r = 0; r < 4; r++) {
        int row = rt * 16 + q * 4 + r;
        if (row < NTOK) {
            #pragma unroll
            for (int ct = 0; ct < 2; ct++)
                aop[(size_t)row * DIM + ct * 16 + c] = (__bf16)(O[rt][ct][r] * inv4[rt][r]);
        }
    }
}

// ---------------------------------------------------------------------------
// Fallback fused MLP (used only if ws_size is too small for the hidden buf).
// ---------------------------------------------------------------------------
__global__ __launch_bounds__(256) void k_mlp(const float* __restrict__ x1,
                                             const float* __restrict__ n2g,
                                             const float* __restrict__ n2b,
                                             const __bf16* __restrict__ fc1T,
                                             const float* __restrict__ fc1b,
                                             const __bf16* __restrict__ fc2T,
                                             const float* __restrict__ fc2b,
                                             float* __restrict__ out) {
    __shared__ __align__(16) char sm[75776];
    __bf16* aT  = (__bf16*)sm;
    float*  lnf = (float*)(sm + 25600);
    __bf16* lB  = (__bf16*)(sm + 25600);
    __bf16* lH  = (__bf16*)(sm + 40960);
    int tid = threadIdx.x;
    int m0 = blockIdx.x * 64;
    int wv = tid >> 6, lane = tid & 63;
    int lrow = lane & 15, lq = lane >> 4;
    int wm = (wv >> 1) * 32, wnb = wv & 1;
    #pragma unroll
    for (int c = 0; c < 12; c++) {
        int idx = tid + c * 256;
        int row = idx / 48, c4 = (idx - row * 48) * 4;
        *(float4*)(lnf + row * 196 + c4) = *(const float4*)(x1 + (size_t)(m0 + row) * DIM + c4);
    }
    __syncthreads();
    {
        int row = tid >> 2, part = tid & 3;
        const float* rp = lnf + row * 196;
        float s = 0.f, s2 = 0.f;
        for (int i = part * 48; i < part * 48 + 48; i++) { float vv = rp[i]; s += vv; s2 += vv * vv; }
        s += __shfl_xor(s, 1); s2 += __shfl_xor(s2, 1);
        s += __shfl_xor(s, 2); s2 += __shfl_xor(s2, 2);
        float mu = s * (1.f / 192.f);
        float rstd = rsqrtf(s2 * (1.f / 192.f) - mu * mu + 1e-5f);
        __bf16* ap = aT + row * 200;
        for (int i = part * 48; i < part * 48 + 48; i++)
            ap[i] = (__bf16)((rp[i] - mu) * rstd * n2g[i] + n2b[i]);
    }
    __syncthreads();
    v4f yacc[2][6] = {};
    for (int hc = 0; hc < 6; hc++) {
        v4f hacc[2][4] = {};
        for (int ks = 0; ks < 6; ks++) {
            #pragma unroll
            for (int c = 0; c < 2; c++) {
                int nrow = (tid >> 2) + c * 64;
                int kc = (tid & 3) * 8;
                *(v8bf*)(lB + nrow * 40 + kc) =
                    *(const v8bf*)(fc1T + (size_t)(hc * 128 + nrow) * DIM + ks * 32 + kc);
            }
            __syncthreads();
            #pragma unroll
            for (int a = 0; a < 2; a++) {
                v8bf af = *(const v8bf*)(aT + (wm + a * 16 + lrow) * 200 + ks * 32 + lq * 8);
                #pragma unroll
                for (int b = 0; b < 4; b++) {
                    v8bf bf = *(const v8bf*)(lB + (wnb * 64 + b * 16 + lrow) * 40 + lq * 8);
                    hacc[a][b] = __builtin_amdgcn_mfma_f32_16x16x32_bf16(af, bf, hacc[a][b], 0, 0, 0);
                }
            }
            __syncthreads();
        }
        #pragma unroll
        for (int a = 0; a < 2; a++)
        #pragma unroll
        for (int b = 0; b < 4; b++)
        #pragma unroll
        for (int r = 0; r < 4; r++) {
            int row = wm + a * 16 + lq * 4 + r;
            int col = wnb * 64 + b * 16 + lrow;
            float hv = hacc[a][b][r] + fc1b[hc * 128 + col];
            float ge = 0.5f * hv * (1.f + erff(hv * 0.70710678118654752f));
            lH[row * 136 + col] = (__bf16)ge;
        }
        __syncthreads();
        for (int k2 = 0; k2 < 4; k2++) {
            #pragma unroll
            for (int c = 0; c < 3; c++) {
                int nrow = (tid >> 2) + c * 64;
                int kc = (tid & 3) * 8;
                *(v8bf*)(lB + nrow * 40 + kc) =
                    *(const v8bf*)(fc2T + (size_t)nrow * HID + hc * 128 + k2 * 32 + kc);
            }
            __syncthreads();
            #pragma unroll
            for (int a = 0; a < 2; a++) {
                v8bf af = *(const v8bf*)(lH + (wm + a * 16 + lrow) * 136 + k2 * 32 + lq * 8);
                #pragma unroll
                for (int b = 0; b < 6; b++) {
                    v8bf bf = *(const v8bf*)(lB + (wnb * 96 + b * 16 + lrow) * 40 + lq * 8);
                    yacc[a][b] = __builtin_amdgcn_mfma_f32_16x16x32_bf16(af, bf, yacc[a][b], 0, 0, 0);
                }
            }
            __syncthreads();
        }
    }
    #pragma unroll
    for (int a = 0; a < 2; a++)
    #pragma unroll
    for (int b = 0; b < 6; b++)
    #pragma unroll
    for (int r = 0; r < 4; r++) {
        int grow = m0 + wm + a * 16 + lq * 4 + r;
        int col = wnb * 96 + b * 16 + lrow;
        float vv = yacc[a][b][r] + fc2b[col] + x1[(size_t)grow * DIM + col];
        out[(size_t)grow * DIM + col] = vv;
    }
}

// ---------------------------------------------------------------------------
extern "C" void kernel_launch(void* const* d_in, const int* in_sizes, int n_in,
                              void* d_out, int out_size, void* d_ws, size_t ws_size,
                              hipStream_t stream) {
    const float* x      = (const float*)d_in[0];
    const float* n1g    = (const float*)d_in[1];
    const float* n1b    = (const float*)d_in[2];
    const float* qkv_w  = (const float*)d_in[3];
    const float* qkv_b  = (const float*)d_in[4];
    const float* rpb    = (const float*)d_in[5];
    const float* proj_w = (const float*)d_in[6];
    const float* proj_b = (const float*)d_in[7];
    const float* n2g    = (const float*)d_in[8];
    const float* n2b    = (const float*)d_in[9];
    const float* fc1_w  = (const float*)d_in[10];
    const float* fc1_b  = (const float*)d_in[11];
    const float* fc2_w  = (const float*)d_in[12];
    const float* fc2_b  = (const float*)d_in[13];
    float* outp = (float*)d_out;

    char* ws = (char*)d_ws;
    const size_t SZA   = (size_t)MTOT * DIM * 2;    //  38,535,168
    const size_t SZHID = (size_t)MTOT * HID * 2;    // 154,140,672 = 4*SZA
    const size_t SZX1  = (size_t)MTOT * DIM * 4;    //  77,070,336 = 2*SZA
    const size_t WSZ   = 884736;                    // transposed weights
    const size_t BSZ   = 4 * HEADS * 64 * 64 * 4;   // bias tables 393,216

    const size_t need_big = SZA + SZHID + SZX1 + WSZ + BSZ;   // ~271 MB
    bool big = (ws_size >= need_big);

    __bf16* xw; __bf16* qb; float* x1; __bf16* a2; __bf16* hid; char* wbase;
    if (big) {
        xw    = (__bf16*)(ws);                    // ln1 out; attn out; a2 overlays
        qb    = (__bf16*)(ws + SZA);              // q,k,v contiguous (3*SZA); hid overlays
        hid   = (__bf16*)(ws + SZA);
        x1    = (float*)(ws + SZA + SZHID);
        a2    = (__bf16*)(ws);
        wbase = ws + SZA + SZHID + SZX1;
    } else {
        xw    = (__bf16*)(ws);
        qb    = (__bf16*)(ws + SZA);
        x1    = (float*)(ws + SZA);               // overlays q+k after attention
        a2    = nullptr; hid = nullptr;
        wbase = ws + SZA + 3 * SZA;
    }
    __bf16* qkvT  = (__bf16*)wbase;
    __bf16* projT = qkvT + 576 * 192;
    __bf16* fc1T  = projT + 192 * 192;
    __bf16* fc2T  = fc1T + 768 * 192;
    float*  btab  = (float*)(fc2T + 768 * 192);

    k_transpose<<<(192 * 576 + 255) / 256, 256, 0, stream>>>(qkv_w, qkvT, 192, 576);
    k_transpose<<<(192 * 192 + 255) / 256, 256, 0, stream>>>(proj_w, projT, 192, 192);
    k_transpose<<<(192 * 768 + 255) / 256, 256, 0, stream>>>(fc1_w, fc1T, 192, 768);
    k_transpose<<<(768 * 192 + 255) / 256, 256, 0, stream>>>(fc2_w, fc2T, 768, 192);
    k_bias<<<dim3(4, HEADS), 256, 0, stream>>>(rpb, btab);

    k_ln1win<<<MTOT / 4, 256, 0, stream>>>(x, n1g, n1b, xw);

    // qkv: [M x 192] x [576 x 192]^T -> scatter q/k/v [w,h,t,32]
    k_gemm128<192, 576, 0><<<dim3(MTOT / 128, 5), 256, 0, stream>>>(
        xw, qkvT, qkv_b, qb, nullptr, nullptr, nullptr);

    k_attn_mfma<<<NWIN * HEADS, 64, 0, stream>>>(qb, btab, xw);

    // proj: [M x 192] x [192 x 192]^T -> x1 f32 (image order, +residual)
    k_gemm128<192, 192, 1><<<dim3(MTOT / 128, 2), 256, 0, stream>>>(
        xw, projT, proj_b, nullptr, nullptr, x1, x);

    if (big) {
        k_ln2<<<MTOT / 4, 256, 0, stream>>>(x1, n2g, n2b, a2);
        k_gemm128<192, 768, 2><<<dim3(MTOT / 128, 6), 256, 0, stream>>>(
            a2, fc1T, fc1_b, hid, nullptr, nullptr, nullptr);
        k_gemm128<768, 192, 3><<<dim3(MTOT / 128, 2), 256, 0, stream>>>(
            hid, fc2T, fc2_b, nullptr, x1, outp, nullptr);
    } else {
        k_mlp<<<MTOT / 64, 256, 0, stream>>>(x1, n2g, n2b, fc1T, fc1_b, fc2T, fc2_b, outp);
    }
}